// Round 1
// baseline (428.136 us; speedup 1.0000x reference)
//
#include <hip/hip_runtime.h>
#include <hip/hip_bf16.h>
#include <stdint.h>

using bf16   = __hip_bfloat16;
using short8 = __attribute__((ext_vector_type(8))) short;
using f32x4  = __attribute__((ext_vector_type(4))) float;

#define NSEQ   2048
#define NHEADS 16
#define DK     64
#define DMODEL 1024
// tokens total = 2*2048 = 4096

#define GLDS16(gp, lp) __builtin_amdgcn_global_load_lds( \
    (const __attribute__((address_space(1))) void*)(gp), \
    (__attribute__((address_space(3))) void*)(lp), 16, 0, 0)

__device__ __forceinline__ ushort f2bf(float f){
  bf16 h = __float2bfloat16(f);
  return __builtin_bit_cast(ushort, h);
}

// ---------------- fp32 -> bf16 convert ----------------
__global__ void k_cvt(const float4* __restrict__ src, ushort4* __restrict__ dst, int n4){
  int i = blockIdx.x*blockDim.x + threadIdx.x;
  if (i >= n4) return;
  float4 v = src[i];
  ushort4 o;
  o.x = f2bf(v.x); o.y = f2bf(v.y); o.z = f2bf(v.z); o.w = f2bf(v.w);
  dst[i] = o;
}

// ---- 128x128 (K=1024) bf16 MFMA GEMM core: C[m,n] = sum_k A[m,k]*B[n,k] ----
// A,B row-major with leading dim 1024. 256 threads = 4 waves; wave w owns the
// 64x64 quadrant (w>>1, w&1); per-wave 4x4 fragments of 16x16x32 MFMA.
__device__ __forceinline__ void gemm_core(
    const ushort* __restrict__ Ap, const ushort* __restrict__ Bp,
    int bm, int bn, int tid, ushort smem[2][2][4096], f32x4 (&acc)[4][4])
{
  const int wave = tid>>6, lane = tid&63;
  const int wr = wave>>1, wc = wave&1;
  const int ko   = (lane>>4)*8;          // k-offset of this lane's fragment
  const int srow = wave*16 + (lane>>2);  // staging row within 64-row chunk
  const int scol = (lane&3)*8;           // staging col (8 bf16 = 16B)

  const ushort* As = Ap + (size_t)(bm*128)*DMODEL + scol;
  const ushort* Bs = Bp + (size_t)(bn*128)*DMODEL + scol;

#define STAGE(buf, kt) do { \
    _Pragma("unroll") \
    for (int i_=0;i_<2;i_++){ \
      GLDS16(As + (size_t)(i_*64 + srow)*DMODEL + (kt)*32, &smem[buf][0][i_*2048 + wave*512]); \
      GLDS16(Bs + (size_t)(i_*64 + srow)*DMODEL + (kt)*32, &smem[buf][1][i_*2048 + wave*512]); \
    } } while(0)

  STAGE(0, 0);
  for (int kt=0; kt<32; ++kt){
    int cur = kt&1;
    __syncthreads();                 // compiler drains vmcnt+lgkmcnt before barrier
    if (kt<31) STAGE(cur^1, kt+1);   // prefetch next K-tile into other buffer
    short8 af[4], bfv[4];
    const ushort* At = smem[cur][0];
    const ushort* Bt = smem[cur][1];
    #pragma unroll
    for (int mi=0;mi<4;mi++) af[mi]  = *(const short8*)&At[(wr*64+mi*16+(lane&15))*32 + ko];
    #pragma unroll
    for (int ni=0;ni<4;ni++) bfv[ni] = *(const short8*)&Bt[(wc*64+ni*16+(lane&15))*32 + ko];
    #pragma unroll
    for (int mi=0;mi<4;mi++)
      #pragma unroll
      for (int ni=0;ni<4;ni++)
        acc[mi][ni] = __builtin_amdgcn_mfma_f32_16x16x32_bf16(af[mi], bfv[ni], acc[mi][ni], 0,0,0);
  }
#undef STAGE
}

// ---------------- fused QKV projection (768 blocks: 256 per output) ----------------
// z=0: Q = (x@Wq^T + bq)*0.125  -> [B,H,N,64]
// z=1: K = (x@Wk^T + bk)        -> [B,H,N,64]
// z=2: Vt = (x@Wv^T + bv)^T     -> [B,H,64,N]   (A/B swapped so MFMA emits V^T)
__global__ __launch_bounds__(256) void k_gemm_qkv(
    const ushort* __restrict__ xb,
    const ushort* __restrict__ Wqb, const ushort* __restrict__ Wkb, const ushort* __restrict__ Wvb,
    const float* __restrict__ bq, const float* __restrict__ bk, const float* __restrict__ bv,
    ushort* __restrict__ Qo, ushort* __restrict__ Ko, ushort* __restrict__ Vto)
{
  __shared__ ushort smem[2][2][4096];
  const int tid = threadIdx.x;
  const int t = blockIdx.x & 255;
  const int z = blockIdx.x >> 8;
  const int lane = tid&63, wave = tid>>6;
  const int wr = wave>>1, wc = wave&1;

  const ushort* Ap; const ushort* Bp; const float* bias;
  ushort* outp; int bm, bn; float scale = 1.0f;
  if (z==0){ Ap=xb;  Bp=Wqb; bias=bq; outp=Qo;  bm=t>>3; bn=t&7; scale=0.125f; }
  else if (z==1){ Ap=xb;  Bp=Wkb; bias=bk; outp=Ko;  bm=t>>3; bn=t&7; }
  else          { Ap=Wvb; Bp=xb;  bias=bv; outp=Vto; bm=t&7;  bn=t>>3; }

  f32x4 acc[4][4] = {};
  gemm_core(Ap, Bp, bm, bn, tid, smem, acc);

  if (z<2){
    #pragma unroll
    for (int mi=0;mi<4;mi++){
      const int m0 = bm*128 + wr*64 + mi*16 + (lane>>4)*4;   // token row
      #pragma unroll
      for (int ni=0;ni<4;ni++){
        const int nn = bn*128 + wc*64 + ni*16 + (lane&15);   // channel
        const float bs = bias[nn];
        const int h = nn>>6, d = nn&63;
        #pragma unroll
        for (int j=0;j<4;j++){
          int mm = m0+j;
          int b = mm>>11, nr = mm&2047;
          size_t off = (((size_t)(b*NHEADS+h)*NSEQ) + nr)*DK + d;
          outp[off] = f2bf((acc[mi][ni][j] + bs)*scale);
        }
      }
    }
  } else {
    #pragma unroll
    for (int mi=0;mi<4;mi++){
      const int m0 = bm*128 + wr*64 + mi*16 + (lane>>4)*4;   // channel row
      #pragma unroll
      for (int ni=0;ni<4;ni++){
        const int nn = bn*128 + wc*64 + ni*16 + (lane&15);   // token
        const int b = nn>>11, nr = nn&2047;
        #pragma unroll
        for (int j=0;j<4;j++){
          int mm = m0+j;
          const float bs = bias[mm];
          int h = mm>>6, d = mm&63;
          size_t off = (((size_t)(b*NHEADS+h)*DK) + d)*NSEQ + nr;
          outp[off] = f2bf(acc[mi][ni][j] + bs);
        }
      }
    }
  }
}

// ---------------- output projection: out = O@Wo^T + bo (fp32 out) ----------------
__global__ __launch_bounds__(256) void k_gemm_out(
    const ushort* __restrict__ Ob, const ushort* __restrict__ Wob,
    const float* __restrict__ bo, float* __restrict__ out)
{
  __shared__ ushort smem[2][2][4096];
  const int tid = threadIdx.x;
  const int t = blockIdx.x;
  const int lane = tid&63, wave = tid>>6;
  const int wr = wave>>1, wc = wave&1;
  const int bm = t>>3, bn = t&7;
  f32x4 acc[4][4] = {};
  gemm_core(Ob, Wob, bm, bn, tid, smem, acc);
  #pragma unroll
  for (int mi=0;mi<4;mi++){
    const int m0 = bm*128 + wr*64 + mi*16 + (lane>>4)*4;
    #pragma unroll
    for (int ni=0;ni<4;ni++){
      const int nn = bn*128 + wc*64 + ni*16 + (lane&15);
      const float bs = bo[nn];
      #pragma unroll
      for (int j=0;j<4;j++)
        out[(size_t)(m0+j)*DMODEL + nn] = acc[mi][ni][j] + bs;
    }
  }
}

// ---------------- flash attention with geometric bias ----------------
// grid (32 qtiles, 16 heads, 2 batch); 4 waves/block; wave owns 16 q-rows.
// S fragment layout (C/D of 16x16x32): row=(lane>>4)*4+reg, col=ni*16+(lane&15).
__global__ __launch_bounds__(256) void k_attn(
    const ushort* __restrict__ Q, const ushort* __restrict__ K, const ushort* __restrict__ Vt,
    const float* __restrict__ pos, const float* __restrict__ dist_bias,
    ushort* __restrict__ O)
{
  __shared__ ushort plds[4][16*72];   // per-wave P tile, row stride 72 (144B, 16B-aligned, conflict-light)
  const int tid = threadIdx.x, wave = tid>>6, lane = tid&63;
  const int qt = blockIdx.x, h = blockIdx.y, b = blockIdx.z;
  const float ah = fabsf(dist_bias[h]);
  const ushort* Qh  = Q  + ((size_t)(b*NHEADS+h))*NSEQ*DK;
  const ushort* Kh  = K  + ((size_t)(b*NHEADS+h))*NSEQ*DK;
  const ushort* Vth = Vt + ((size_t)(b*NHEADS+h))*DK*NSEQ;
  const float*  pb  = pos + (size_t)b*NSEQ*3;
  const int ko = (lane>>4)*8;
  const int i0 = qt*64 + wave*16;

  // Q fragments (A operand): row = i0 + (lane&15)
  const int ia = i0 + (lane&15);
  short8 qa0 = *(const short8*)&Qh[(size_t)ia*DK + ko];
  short8 qa1 = *(const short8*)&Qh[(size_t)ia*DK + 32 + ko];

  // i-side geometry for softmax rows i0 + (lane>>4)*4 + r
  float pqx[4],pqy[4],pqz[4],sqq[4];
  #pragma unroll
  for (int r=0;r<4;r++){
    int i = i0 + (lane>>4)*4 + r;
    const float* p = pb + (size_t)i*3;
    pqx[r]=p[0]; pqy[r]=p[1]; pqz[r]=p[2];
    sqq[r] = pqx[r]*pqx[r] + pqy[r]*pqy[r] + pqz[r]*pqz[r];
  }

  f32x4 oacc[4] = {};
  float mrun[4], lrun[4];
  #pragma unroll
  for (int r=0;r<4;r++){ mrun[r] = -1e30f; lrun[r] = 0.f; }

  ushort* pl = plds[wave];

  for (int jt=0; jt<32; ++jt){
    const int jb = jt*64;
    // ---- S = Q K^T (pre-scaled Q) ----
    f32x4 s[4];
    #pragma unroll
    for (int ni=0;ni<4;ni++){
      const int jr = jb + ni*16 + (lane&15);
      short8 kb0 = *(const short8*)&Kh[(size_t)jr*DK + ko];
      short8 kb1 = *(const short8*)&Kh[(size_t)jr*DK + 32 + ko];
      f32x4 z = {};
      z = __builtin_amdgcn_mfma_f32_16x16x32_bf16(qa0, kb0, z, 0,0,0);
      z = __builtin_amdgcn_mfma_f32_16x16x32_bf16(qa1, kb1, z, 0,0,0);
      s[ni] = z;
    }
    // ---- geometric bias (fp32) ----
    float pkx[4],pky[4],pkz[4],sqk[4];
    #pragma unroll
    for (int ni=0;ni<4;ni++){
      int j = jb + ni*16 + (lane&15);
      const float* p = pb + (size_t)j*3;
      pkx[ni]=p[0]; pky[ni]=p[1]; pkz[ni]=p[2];
      sqk[ni] = pkx[ni]*pkx[ni] + pky[ni]*pky[ni] + pkz[ni]*pkz[ni];
    }
    #pragma unroll
    for (int ni=0;ni<4;ni++){
      #pragma unroll
      for (int r=0;r<4;r++){
        float d2 = sqq[r] + sqk[ni] - 2.f*(pqx[r]*pkx[ni] + pqy[r]*pky[ni] + pqz[r]*pkz[ni]);
        d2 = fmaxf(d2, 0.f);
        float dd = sqrtf(d2);
        s[ni][r] += __logf(__expf(-ah*dd) + 1e-8f);
      }
    }
    // ---- online softmax (rows split across 16 lanes of same lane>>4 group) ----
    float mx[4];
    #pragma unroll
    for (int r=0;r<4;r++)
      mx[r] = fmaxf(fmaxf(s[0][r], s[1][r]), fmaxf(s[2][r], s[3][r]));
    #pragma unroll
    for (int m=1;m<16;m<<=1){
      #pragma unroll
      for (int r=0;r<4;r++) mx[r] = fmaxf(mx[r], __shfl_xor(mx[r], m));
    }
    float scl[4];
    #pragma unroll
    for (int r=0;r<4;r++){
      float mn = fmaxf(mrun[r], mx[r]);
      scl[r] = __expf(mrun[r]-mn);
      mrun[r] = mn;
    }
    #pragma unroll
    for (int ni=0;ni<4;ni++)
      #pragma unroll
      for (int r=0;r<4;r++)
        s[ni][r] = __expf(s[ni][r] - mrun[r]);
    float rs[4];
    #pragma unroll
    for (int r=0;r<4;r++) rs[r] = s[0][r]+s[1][r]+s[2][r]+s[3][r];
    #pragma unroll
    for (int m=1;m<16;m<<=1){
      #pragma unroll
      for (int r=0;r<4;r++) rs[r] += __shfl_xor(rs[r], m);
    }
    #pragma unroll
    for (int r=0;r<4;r++) lrun[r] = lrun[r]*scl[r] + rs[r];
    #pragma unroll
    for (int ni=0;ni<4;ni++)
      #pragma unroll
      for (int r=0;r<4;r++)
        oacc[ni][r] *= scl[r];
    // ---- P -> LDS (transpose to A-operand layout) ----
    #pragma unroll
    for (int ni=0;ni<4;ni++)
      #pragma unroll
      for (int r=0;r<4;r++)
        pl[((lane>>4)*4+r)*72 + ni*16 + (lane&15)] = f2bf(s[ni][r]);
    asm volatile("s_waitcnt lgkmcnt(0)" ::: "memory");
    // ---- O += P V  (B-operand = Vt rows, contiguous 16B) ----
    #pragma unroll
    for (int kk=0;kk<2;kk++){
      short8 pa = *(const short8*)&pl[(lane&15)*72 + kk*32 + ko];
      #pragma unroll
      for (int ni=0;ni<4;ni++){
        const int d = ni*16 + (lane&15);
        short8 vb = *(const short8*)&Vth[(size_t)d*NSEQ + jb + kk*32 + ko];
        oacc[ni] = __builtin_amdgcn_mfma_f32_16x16x32_bf16(pa, vb, oacc[ni], 0,0,0);
      }
    }
  }
  // ---- normalize + write O[b, i, h*64+d] (bf16, [B,N,1024] for out-proj) ----
  #pragma unroll
  for (int ni=0;ni<4;ni++){
    #pragma unroll
    for (int r=0;r<4;r++){
      int i = i0 + (lane>>4)*4 + r;
      int d = ni*16 + (lane&15);
      float val = oacc[ni][r] / lrun[r];
      O[((size_t)b*NSEQ + i)*DMODEL + h*DK + d] = f2bf(val);
    }
  }
}

extern "C" void kernel_launch(void* const* d_in, const int* in_sizes, int n_in,
                              void* d_out, int out_size, void* d_ws, size_t ws_size,
                              hipStream_t stream) {
  const float* x   = (const float*)d_in[0];
  const float* pos = (const float*)d_in[1];
  const float* Wq  = (const float*)d_in[2];
  const float* bq  = (const float*)d_in[3];
  const float* Wk  = (const float*)d_in[4];
  const float* bk  = (const float*)d_in[5];
  const float* Wv  = (const float*)d_in[6];
  const float* bv  = (const float*)d_in[7];
  const float* Wo  = (const float*)d_in[8];
  const float* bo  = (const float*)d_in[9];
  const float* db  = (const float*)d_in[10];
  float* out = (float*)d_out;

  // workspace layout (48 MB total)
  char* ws = (char*)d_ws;
  ushort* xb  = (ushort*)(ws);                      // 8 MB  x bf16 [4096][1024]
  ushort* Wqb = (ushort*)(ws + ((size_t)8<<20));    // 2 MB
  ushort* Wkb = (ushort*)(ws + ((size_t)10<<20));   // 2 MB
  ushort* Wvb = (ushort*)(ws + ((size_t)12<<20));   // 2 MB
  ushort* Wob = (ushort*)(ws + ((size_t)14<<20));   // 2 MB
  ushort* Qb  = (ushort*)(ws + ((size_t)16<<20));   // 8 MB  [B,H,N,64] (pre-scaled)
  ushort* Kb  = (ushort*)(ws + ((size_t)24<<20));   // 8 MB  [B,H,N,64]
  ushort* Vtb = (ushort*)(ws + ((size_t)32<<20));   // 8 MB  [B,H,64,N]
  ushort* Ob  = (ushort*)(ws + ((size_t)40<<20));   // 8 MB  [B,N,1024]

  k_cvt<<<4096, 256, 0, stream>>>((const float4*)x,  (ushort4*)xb,  1048576);
  k_cvt<<<1024, 256, 0, stream>>>((const float4*)Wq, (ushort4*)Wqb, 262144);
  k_cvt<<<1024, 256, 0, stream>>>((const float4*)Wk, (ushort4*)Wkb, 262144);
  k_cvt<<<1024, 256, 0, stream>>>((const float4*)Wv, (ushort4*)Wvb, 262144);
  k_cvt<<<1024, 256, 0, stream>>>((const float4*)Wo, (ushort4*)Wob, 262144);
  k_gemm_qkv<<<768, 256, 0, stream>>>(xb, Wqb, Wkb, Wvb, bq, bk, bv, Qb, Kb, Vtb);
  k_attn<<<dim3(32,16,2), 256, 0, stream>>>(Qb, Kb, Vtb, pos, db, Ob);
  k_gemm_out<<<256, 256, 0, stream>>>(Ob, Wob, bo, out);
}

// Round 2
// 380.250 us; speedup vs baseline: 1.1259x; 1.1259x over previous
//
#include <hip/hip_runtime.h>
#include <hip/hip_bf16.h>
#include <stdint.h>

using bf16   = __hip_bfloat16;
using short8 = __attribute__((ext_vector_type(8))) short;
using f32x4  = __attribute__((ext_vector_type(4))) float;
using f32x16 = __attribute__((ext_vector_type(16))) float;

#define NSEQ   2048
#define NHEADS 16
#define DK     64
#define DMODEL 1024

#define GLDS16(gp, lp) __builtin_amdgcn_global_load_lds( \
    (const __attribute__((address_space(1))) void*)(gp), \
    (__attribute__((address_space(3))) void*)(lp), 16, 0, 0)

__device__ __forceinline__ ushort f2bf(float f){
  bf16 h = __float2bfloat16(f);
  return __builtin_bit_cast(ushort, h);
}

// ---------------- fp32 -> bf16 convert ----------------
__global__ void k_cvt(const float4* __restrict__ src, ushort4* __restrict__ dst, int n4){
  int i = blockIdx.x*blockDim.x + threadIdx.x;
  if (i >= n4) return;
  float4 v = src[i];
  ushort4 o;
  o.x = f2bf(v.x); o.y = f2bf(v.y); o.z = f2bf(v.z); o.w = f2bf(v.w);
  dst[i] = o;
}

// ---------------- positions -> (x,y,z,|p|^2) ----------------
__global__ void k_pos4(const float* __restrict__ pos, float4* __restrict__ pos4, int n){
  int i = blockIdx.x*blockDim.x + threadIdx.x;
  if (i >= n) return;
  float x = pos[i*3+0], y = pos[i*3+1], z = pos[i*3+2];
  float4 o; o.x=x; o.y=y; o.z=z; o.w = x*x + y*y + z*z;
  pos4[i] = o;
}

// ---- 128x128 (K=1024) bf16 MFMA GEMM core: C[m,n] = sum_k A[m,k]*B[n,k] ----
__device__ __forceinline__ void gemm_core(
    const ushort* __restrict__ Ap, const ushort* __restrict__ Bp,
    int bm, int bn, int tid, ushort smem[2][2][4096], f32x4 (&acc)[4][4])
{
  const int wave = tid>>6, lane = tid&63;
  const int wr = wave>>1, wc = wave&1;
  const int ko   = (lane>>4)*8;
  const int srow = wave*16 + (lane>>2);
  const int scol = (lane&3)*8;

  const ushort* As = Ap + (size_t)(bm*128)*DMODEL + scol;
  const ushort* Bs = Bp + (size_t)(bn*128)*DMODEL + scol;

#define STAGE(buf, kt) do { \
    _Pragma("unroll") \
    for (int i_=0;i_<2;i_++){ \
      GLDS16(As + (size_t)(i_*64 + srow)*DMODEL + (kt)*32, &smem[buf][0][i_*2048 + wave*512]); \
      GLDS16(Bs + (size_t)(i_*64 + srow)*DMODEL + (kt)*32, &smem[buf][1][i_*2048 + wave*512]); \
    } } while(0)

  STAGE(0, 0);
  for (int kt=0; kt<32; ++kt){
    int cur = kt&1;
    __syncthreads();
    if (kt<31) STAGE(cur^1, kt+1);
    short8 af[4], bfv[4];
    const ushort* At = smem[cur][0];
    const ushort* Bt = smem[cur][1];
    #pragma unroll
    for (int mi=0;mi<4;mi++) af[mi]  = *(const short8*)&At[(wr*64+mi*16+(lane&15))*32 + ko];
    #pragma unroll
    for (int ni=0;ni<4;ni++) bfv[ni] = *(const short8*)&Bt[(wc*64+ni*16+(lane&15))*32 + ko];
    #pragma unroll
    for (int mi=0;mi<4;mi++)
      #pragma unroll
      for (int ni=0;ni<4;ni++)
        acc[mi][ni] = __builtin_amdgcn_mfma_f32_16x16x32_bf16(af[mi], bfv[ni], acc[mi][ni], 0,0,0);
  }
#undef STAGE
}

// ---------------- fused QKV projection ----------------
__global__ __launch_bounds__(256) void k_gemm_qkv(
    const ushort* __restrict__ xb,
    const ushort* __restrict__ Wqb, const ushort* __restrict__ Wkb, const ushort* __restrict__ Wvb,
    const float* __restrict__ bq, const float* __restrict__ bk, const float* __restrict__ bv,
    ushort* __restrict__ Qo, ushort* __restrict__ Ko, ushort* __restrict__ Vto)
{
  __shared__ ushort smem[2][2][4096];
  const int tid = threadIdx.x;
  const int t = blockIdx.x & 255;
  const int z = blockIdx.x >> 8;
  const int lane = tid&63, wave = tid>>6;
  const int wr = wave>>1, wc = wave&1;

  const ushort* Ap; const ushort* Bp; const float* bias;
  ushort* outp; int bm, bn; float scale = 1.0f;
  if (z==0){ Ap=xb;  Bp=Wqb; bias=bq; outp=Qo;  bm=t>>3; bn=t&7; scale=0.125f; }
  else if (z==1){ Ap=xb;  Bp=Wkb; bias=bk; outp=Ko;  bm=t>>3; bn=t&7; }
  else          { Ap=Wvb; Bp=xb;  bias=bv; outp=Vto; bm=t&7;  bn=t>>3; }

  f32x4 acc[4][4] = {};
  gemm_core(Ap, Bp, bm, bn, tid, smem, acc);

  if (z<2){
    #pragma unroll
    for (int mi=0;mi<4;mi++){
      const int m0 = bm*128 + wr*64 + mi*16 + (lane>>4)*4;
      #pragma unroll
      for (int ni=0;ni<4;ni++){
        const int nn = bn*128 + wc*64 + ni*16 + (lane&15);
        const float bs = bias[nn];
        const int h = nn>>6, d = nn&63;
        #pragma unroll
        for (int j=0;j<4;j++){
          int mm = m0+j;
          int b = mm>>11, nr = mm&2047;
          size_t off = (((size_t)(b*NHEADS+h)*NSEQ) + nr)*DK + d;
          outp[off] = f2bf((acc[mi][ni][j] + bs)*scale);
        }
      }
    }
  } else {
    #pragma unroll
    for (int mi=0;mi<4;mi++){
      const int m0 = bm*128 + wr*64 + mi*16 + (lane>>4)*4;
      #pragma unroll
      for (int ni=0;ni<4;ni++){
        const int nn = bn*128 + wc*64 + ni*16 + (lane&15);
        const int b = nn>>11, nr = nn&2047;
        #pragma unroll
        for (int j=0;j<4;j++){
          int mm = m0+j;
          const float bs = bias[mm];
          int h = mm>>6, d = mm&63;
          size_t off = (((size_t)(b*NHEADS+h)*DK) + d)*NSEQ + nr;
          outp[off] = f2bf(acc[mi][ni][j] + bs);
        }
      }
    }
  }
}

// ---------------- output projection ----------------
__global__ __launch_bounds__(256) void k_gemm_out(
    const ushort* __restrict__ Ob, const ushort* __restrict__ Wob,
    const float* __restrict__ bo, float* __restrict__ out)
{
  __shared__ ushort smem[2][2][4096];
  const int tid = threadIdx.x;
  const int t = blockIdx.x;
  const int lane = tid&63, wave = tid>>6;
  const int wr = wave>>1, wc = wave&1;
  const int bm = t>>3, bn = t&7;
  f32x4 acc[4][4] = {};
  gemm_core(Ob, Wob, bm, bn, tid, smem, acc);
  #pragma unroll
  for (int mi=0;mi<4;mi++){
    const int m0 = bm*128 + wr*64 + mi*16 + (lane>>4)*4;
    #pragma unroll
    for (int ni=0;ni<4;ni++){
      const int nn = bn*128 + wc*64 + ni*16 + (lane&15);
      const float bs = bo[nn];
      #pragma unroll
      for (int j=0;j<4;j++)
        out[(size_t)(m0+j)*DMODEL + nn] = acc[mi][ni][j] + bs;
    }
  }
}

// ---------------- flash attention, swapped-QK 32x32 structure ----------------
// 2 waves/block, each wave owns 32 q-rows. mfma(A=K, B=Q) -> S^T fragment:
// q = lane&31, k = crow(r,hi) = (r&3)+8*(r>>2)+4*hi. Row softmax is in-lane
// (15 ops) + one shfl_xor(32). bias = -|a|*d added directly (log(exp)+eps
// identity; error < 2e-3 in the softmax-relevant range). P -> PV A-operand
// via v_cvt_pk_bf16_f32 + v_permlane32_swap_b32 (no LDS). Defer-max THR=8.
__global__ __launch_bounds__(128) void k_attn(
    const ushort* __restrict__ Q, const ushort* __restrict__ K, const ushort* __restrict__ Vt,
    const float4* __restrict__ pos4, const float* __restrict__ dist_bias,
    ushort* __restrict__ O)
{
  const int tid = threadIdx.x, wave = tid>>6, lane = tid&63;
  const int qt = blockIdx.x, h = blockIdx.y, b = blockIdx.z;
  const int lo5 = lane&31, hi = lane>>5;
  const float ah = fabsf(dist_bias[h]);
  const ushort* Qh  = Q  + ((size_t)(b*NHEADS+h))*NSEQ*DK;
  const ushort* Kh  = K  + ((size_t)(b*NHEADS+h))*NSEQ*DK;
  const ushort* Vth = Vt + ((size_t)(b*NHEADS+h))*DK*NSEQ;
  const float4* pb  = pos4 + (size_t)b*NSEQ;

  const int q0 = qt*64 + wave*32;

  // Q B-fragments: col=q0+lo5, k = s*16 + hi*8 + e
  short8 qf[4];
  #pragma unroll
  for (int s=0;s<4;s++)
    qf[s] = *(const short8*)&Qh[(size_t)(q0+lo5)*DK + s*16 + hi*8];

  const float4 pq = pb[q0 + lo5];

  f32x16 o0 = {}, o1 = {};
  float m_run = -1e30f, l_run = 0.f;

  for (int jt=0; jt<64; ++jt){
    const int jb = jt*32;
    // ---- S^T = K Q^T (Q pre-scaled by 1/8) ----
    f32x16 st = {};
    #pragma unroll
    for (int s=0;s<4;s++){
      short8 kf = *(const short8*)&Kh[(size_t)(jb+lo5)*DK + s*16 + hi*8];
      st = __builtin_amdgcn_mfma_f32_32x32x16_bf16(kf, qf[s], st, 0,0,0);
    }
    // ---- bias -a*d + row max ----
    float p[16];
    float pmax = -1e30f;
    #pragma unroll
    for (int r=0;r<16;r++){
      const int krow = jb + (r&3) + 8*(r>>2) + 4*hi;
      float4 pk = pb[krow];
      float t = pq.x*pk.x;
      t = fmaf(pq.y, pk.y, t);
      t = fmaf(pq.z, pk.z, t);
      float d2 = fmaxf(fmaf(-2.f, t, pq.w + pk.w), 0.f);
      float sv = fmaf(-ah, __builtin_sqrtf(d2), st[r]);
      p[r] = sv;
      pmax = fmaxf(pmax, sv);
    }
    pmax = fmaxf(pmax, __shfl_xor(pmax, 32));
    // ---- deferred-max online softmax ----
    if (__any(pmax - m_run > 8.f)){
      const float m_new = fmaxf(m_run, pmax);
      const float f = __expf(m_run - m_new);
      l_run *= f;
      #pragma unroll
      for (int r=0;r<16;r++){
        const int src = (r&3) + 8*(r>>2) + 4*hi;
        const float fr = __shfl(f, src);
        o0[r] *= fr; o1[r] *= fr;
      }
      m_run = m_new;
    }
    float rsum = 0.f;
    #pragma unroll
    for (int r=0;r<16;r++){
      p[r] = __expf(p[r] - m_run);
      rsum += p[r];
    }
    rsum += __shfl_xor(rsum, 32);
    l_run += rsum;
    // ---- P -> bf16 A-fragments (cvt_pk + permlane32_swap), PV ----
    #pragma unroll
    for (int s=0;s<2;s++){
      uint w0, w1, w2, w3;
      asm("v_cvt_pk_bf16_f32 %0, %1, %2" : "=v"(w0) : "v"(p[8*s+0]), "v"(p[8*s+1]));
      asm("v_cvt_pk_bf16_f32 %0, %1, %2" : "=v"(w2) : "v"(p[8*s+4]), "v"(p[8*s+5]));
      asm("v_cvt_pk_bf16_f32 %0, %1, %2" : "=v"(w1) : "v"(p[8*s+2]), "v"(p[8*s+3]));
      asm("v_cvt_pk_bf16_f32 %0, %1, %2" : "=v"(w3) : "v"(p[8*s+6]), "v"(p[8*s+7]));
      // vdst.hi-lanes <-> src0.lo-lanes: (w0,w2) -> (k0..1|k8..9, k4..5|k12..13)
      asm volatile("v_permlane32_swap_b32 %0, %1" : "+v"(w0), "+v"(w2));
      asm volatile("v_permlane32_swap_b32 %0, %1" : "+v"(w1), "+v"(w3));
      uint4 aw; aw.x = w0; aw.y = w1; aw.z = w2; aw.w = w3;
      const short8 pa = __builtin_bit_cast(short8, aw);
      const short8 v0 = *(const short8*)&Vth[(size_t)(0*32+lo5)*NSEQ + jb + s*16 + hi*8];
      const short8 v1 = *(const short8*)&Vth[(size_t)(1*32+lo5)*NSEQ + jb + s*16 + hi*8];
      o0 = __builtin_amdgcn_mfma_f32_32x32x16_bf16(pa, v0, o0, 0,0,0);
      o1 = __builtin_amdgcn_mfma_f32_32x32x16_bf16(pa, v1, o1, 0,0,0);
    }
  }
  // ---- normalize + store: O row q=crow(r,hi), col d = dh*32 + lo5 ----
  #pragma unroll
  for (int r=0;r<16;r++){
    const int src = (r&3) + 8*(r>>2) + 4*hi;
    const float lr = __shfl(l_run, src);
    const float inv = 1.f/lr;
    const int i = q0 + src;
    O[((size_t)b*NSEQ + i)*DMODEL + h*DK + lo5]      = f2bf(o0[r]*inv);
    O[((size_t)b*NSEQ + i)*DMODEL + h*DK + 32 + lo5] = f2bf(o1[r]*inv);
  }
}

extern "C" void kernel_launch(void* const* d_in, const int* in_sizes, int n_in,
                              void* d_out, int out_size, void* d_ws, size_t ws_size,
                              hipStream_t stream) {
  const float* x   = (const float*)d_in[0];
  const float* pos = (const float*)d_in[1];
  const float* Wq  = (const float*)d_in[2];
  const float* bq  = (const float*)d_in[3];
  const float* Wk  = (const float*)d_in[4];
  const float* bk  = (const float*)d_in[5];
  const float* Wv  = (const float*)d_in[6];
  const float* bv  = (const float*)d_in[7];
  const float* Wo  = (const float*)d_in[8];
  const float* bo  = (const float*)d_in[9];
  const float* db  = (const float*)d_in[10];
  float* out = (float*)d_out;

  // workspace layout (48 MB total)
  char* ws = (char*)d_ws;
  ushort* xb  = (ushort*)(ws);                      // 8 MB
  ushort* Wqb = (ushort*)(ws + ((size_t)8<<20));    // 2 MB (reused as pos4 after qkv gemm)
  ushort* Wkb = (ushort*)(ws + ((size_t)10<<20));   // 2 MB
  ushort* Wvb = (ushort*)(ws + ((size_t)12<<20));   // 2 MB
  ushort* Wob = (ushort*)(ws + ((size_t)14<<20));   // 2 MB
  ushort* Qb  = (ushort*)(ws + ((size_t)16<<20));   // 8 MB  [B,H,N,64] (pre-scaled)
  ushort* Kb  = (ushort*)(ws + ((size_t)24<<20));   // 8 MB  [B,H,N,64]
  ushort* Vtb = (ushort*)(ws + ((size_t)32<<20));   // 8 MB  [B,H,64,N]
  ushort* Ob  = (ushort*)(ws + ((size_t)40<<20));   // 8 MB  [B,N,1024]
  float4* pos4 = (float4*)Wqb;                      // 64 KB, alive only after qkv gemm

  k_cvt<<<4096, 256, 0, stream>>>((const float4*)x,  (ushort4*)xb,  1048576);
  k_cvt<<<1024, 256, 0, stream>>>((const float4*)Wq, (ushort4*)Wqb, 262144);
  k_cvt<<<1024, 256, 0, stream>>>((const float4*)Wk, (ushort4*)Wkb, 262144);
  k_cvt<<<1024, 256, 0, stream>>>((const float4*)Wv, (ushort4*)Wvb, 262144);
  k_cvt<<<1024, 256, 0, stream>>>((const float4*)Wo, (ushort4*)Wob, 262144);
  k_gemm_qkv<<<768, 256, 0, stream>>>(xb, Wqb, Wkb, Wvb, bq, bk, bv, Qb, Kb, Vtb);
  k_pos4<<<16, 256, 0, stream>>>(pos, pos4, 2*NSEQ);
  k_attn<<<dim3(32,NHEADS,2), 128, 0, stream>>>(Qb, Kb, Vtb, pos4, db, Ob);
  k_gemm_out<<<256, 256, 0, stream>>>(Ob, Wob, bo, out);
}

// Round 4
// 290.588 us; speedup vs baseline: 1.4733x; 1.3086x over previous
//
#include <hip/hip_runtime.h>
#include <hip/hip_bf16.h>
#include <stdint.h>

using bf16   = __hip_bfloat16;
using short8 = __attribute__((ext_vector_type(8))) short;
using f32x4  = __attribute__((ext_vector_type(4))) float;
using f32x16 = __attribute__((ext_vector_type(16))) float;

#define NSEQ   2048
#define NHEADS 16
#define DK     64
#define DMODEL 1024

#define GLDS16(gp, lp) __builtin_amdgcn_global_load_lds( \
    (const __attribute__((address_space(1))) void*)(gp), \
    (__attribute__((address_space(3))) void*)(lp), 16, 0, 0)

__device__ __forceinline__ ushort f2bf(float f){
  bf16 h = __float2bfloat16(f);
  return __builtin_bit_cast(ushort, h);
}
__device__ __forceinline__ float bf2f(ushort u){
  uint t = ((uint)u)<<16; return __builtin_bit_cast(float, t);
}

// ---------------- fp32 -> bf16 convert ----------------
__global__ void k_cvt(const float4* __restrict__ src, ushort4* __restrict__ dst, int n4){
  int i = blockIdx.x*blockDim.x + threadIdx.x;
  if (i >= n4) return;
  float4 v = src[i];
  ushort4 o;
  o.x = f2bf(v.x); o.y = f2bf(v.y); o.z = f2bf(v.z); o.w = f2bf(v.w);
  dst[i] = o;
}

// ---------------- geometry feature tables (bf16 hi/lo split) ----------------
// d^2(q,k) = dot(AF[k], BF[q]) over 16 slots:
// AF = [xh,xl,xh, yh,yl,yh, zh,zl,zh, sh,sl, 1,1, 0,0,0]
// BF = [-2xh,-2xh,-2xl, -2yh,-2yh,-2yl, -2zh,-2zh,-2zl, 1,1, sh,sl, 0,0,0]
__global__ void k_geo(const float* __restrict__ pos, ushort* __restrict__ AF,
                      ushort* __restrict__ BF, int n){
  int i = blockIdx.x*blockDim.x + threadIdx.x;
  if (i >= n) return;
  float x = pos[i*3+0], y = pos[i*3+1], z = pos[i*3+2];
  float sq = x*x + y*y + z*z;
  ushort xh = f2bf(x);  float xhf = bf2f(xh);  ushort xl = f2bf(x - xhf);
  ushort yh = f2bf(y);  float yhf = bf2f(yh);  ushort yl = f2bf(y - yhf);
  ushort zh = f2bf(z);  float zhf = bf2f(zh);  ushort zl = f2bf(z - zhf);
  ushort sh = f2bf(sq); float shf = bf2f(sh);  ushort sl = f2bf(sq - shf);
  ushort m2xh = f2bf(-2.f*xhf), m2xl = f2bf(-2.f*bf2f(xl));
  ushort m2yh = f2bf(-2.f*yhf), m2yl = f2bf(-2.f*bf2f(yl));
  ushort m2zh = f2bf(-2.f*zhf), m2zl = f2bf(-2.f*bf2f(zl));
  const ushort one = 0x3F80;
  ushort af[16] = {xh,xl,xh, yh,yl,yh, zh,zl,zh, sh,sl, one,one, 0,0,0};
  ushort bv[16] = {m2xh,m2xh,m2xl, m2yh,m2yh,m2yl, m2zh,m2zh,m2zl, one,one, sh,sl, 0,0,0};
  *(uint4*)&AF[i*16]     = *(uint4*)&af[0];
  *(uint4*)&AF[i*16 + 8] = *(uint4*)&af[8];
  *(uint4*)&BF[i*16]     = *(uint4*)&bv[0];
  *(uint4*)&BF[i*16 + 8] = *(uint4*)&bv[8];
}

// ---- 128x128 (K=1024) bf16 MFMA GEMM core: C[m,n] = sum_k A[m,k]*B[n,k] ----
__device__ __forceinline__ void gemm_core(
    const ushort* __restrict__ Ap, const ushort* __restrict__ Bp,
    int bm, int bn, int tid, ushort smem[2][2][4096], f32x4 (&acc)[4][4])
{
  const int wave = tid>>6, lane = tid&63;
  const int wr = wave>>1, wc = wave&1;
  const int ko   = (lane>>4)*8;
  const int srow = wave*16 + (lane>>2);
  const int scol = (lane&3)*8;

  const ushort* As = Ap + (size_t)(bm*128)*DMODEL + scol;
  const ushort* Bs = Bp + (size_t)(bn*128)*DMODEL + scol;

#define STAGE(buf, kt) do { \
    _Pragma("unroll") \
    for (int i_=0;i_<2;i_++){ \
      GLDS16(As + (size_t)(i_*64 + srow)*DMODEL + (kt)*32, &smem[buf][0][i_*2048 + wave*512]); \
      GLDS16(Bs + (size_t)(i_*64 + srow)*DMODEL + (kt)*32, &smem[buf][1][i_*2048 + wave*512]); \
    } } while(0)

  STAGE(0, 0);
  for (int kt=0; kt<32; ++kt){
    int cur = kt&1;
    __syncthreads();
    if (kt<31) STAGE(cur^1, kt+1);
    short8 af[4], bfv[4];
    const ushort* At = smem[cur][0];
    const ushort* Bt = smem[cur][1];
    #pragma unroll
    for (int mi=0;mi<4;mi++) af[mi]  = *(const short8*)&At[(wr*64+mi*16+(lane&15))*32 + ko];
    #pragma unroll
    for (int ni=0;ni<4;ni++) bfv[ni] = *(const short8*)&Bt[(wc*64+ni*16+(lane&15))*32 + ko];
    #pragma unroll
    for (int mi=0;mi<4;mi++)
      #pragma unroll
      for (int ni=0;ni<4;ni++)
        acc[mi][ni] = __builtin_amdgcn_mfma_f32_16x16x32_bf16(af[mi], bfv[ni], acc[mi][ni], 0,0,0);
  }
#undef STAGE
}

// ---------------- fused QKV projection ----------------
__global__ __launch_bounds__(256) void k_gemm_qkv(
    const ushort* __restrict__ xb,
    const ushort* __restrict__ Wqb, const ushort* __restrict__ Wkb, const ushort* __restrict__ Wvb,
    const float* __restrict__ bq, const float* __restrict__ bk, const float* __restrict__ bv,
    ushort* __restrict__ Qo, ushort* __restrict__ Ko, ushort* __restrict__ Vto)
{
  __shared__ ushort smem[2][2][4096];
  const int tid = threadIdx.x;
  const int t = blockIdx.x & 255;
  const int z = blockIdx.x >> 8;
  const int lane = tid&63, wave = tid>>6;
  const int wr = wave>>1, wc = wave&1;

  const ushort* Ap; const ushort* Bp; const float* bias;
  ushort* outp; int bm, bn; float scale = 1.0f;
  if (z==0){ Ap=xb;  Bp=Wqb; bias=bq; outp=Qo;  bm=t>>3; bn=t&7; scale=0.125f; }
  else if (z==1){ Ap=xb;  Bp=Wkb; bias=bk; outp=Ko;  bm=t>>3; bn=t&7; }
  else          { Ap=Wvb; Bp=xb;  bias=bv; outp=Vto; bm=t&7;  bn=t>>3; }

  f32x4 acc[4][4] = {};
  gemm_core(Ap, Bp, bm, bn, tid, smem, acc);

  if (z<2){
    #pragma unroll
    for (int mi=0;mi<4;mi++){
      const int m0 = bm*128 + wr*64 + mi*16 + (lane>>4)*4;
      #pragma unroll
      for (int ni=0;ni<4;ni++){
        const int nn = bn*128 + wc*64 + ni*16 + (lane&15);
        const float bs = bias[nn];
        const int h = nn>>6, d = nn&63;
        #pragma unroll
        for (int j=0;j<4;j++){
          int mm = m0+j;
          int b = mm>>11, nr = mm&2047;
          size_t off = (((size_t)(b*NHEADS+h)*NSEQ) + nr)*DK + d;
          outp[off] = f2bf((acc[mi][ni][j] + bs)*scale);
        }
      }
    }
  } else {
    #pragma unroll
    for (int mi=0;mi<4;mi++){
      const int m0 = bm*128 + wr*64 + mi*16 + (lane>>4)*4;
      #pragma unroll
      for (int ni=0;ni<4;ni++){
        const int nn = bn*128 + wc*64 + ni*16 + (lane&15);
        const int b = nn>>11, nr = nn&2047;
        #pragma unroll
        for (int j=0;j<4;j++){
          int mm = m0+j;
          const float bs = bias[mm];
          int h = mm>>6, d = mm&63;
          size_t off = (((size_t)(b*NHEADS+h)*DK) + d)*NSEQ + nr;
          outp[off] = f2bf(acc[mi][ni][j] + bs);
        }
      }
    }
  }
}

// ---------------- output projection ----------------
__global__ __launch_bounds__(256) void k_gemm_out(
    const ushort* __restrict__ Ob, const ushort* __restrict__ Wob,
    const float* __restrict__ bo, float* __restrict__ out)
{
  __shared__ ushort smem[2][2][4096];
  const int tid = threadIdx.x;
  const int t = blockIdx.x;
  const int lane = tid&63, wave = tid>>6;
  const int wr = wave>>1, wc = wave&1;
  const int bm = t>>3, bn = t&7;
  f32x4 acc[4][4] = {};
  gemm_core(Ob, Wob, bm, bn, tid, smem, acc);
  #pragma unroll
  for (int mi=0;mi<4;mi++){
    const int m0 = bm*128 + wr*64 + mi*16 + (lane>>4)*4;
    #pragma unroll
    for (int ni=0;ni<4;ni++){
      const int nn = bn*128 + wc*64 + ni*16 + (lane&15);
      const float bs = bo[nn];
      #pragma unroll
      for (int j=0;j<4;j++)
        out[(size_t)(m0+j)*DMODEL + nn] = acc[mi][ni][j] + bs;
    }
  }
}

// ---------------- flash attention: swapped-QK 32x32, d^2 via MFMA, no max ----------------
// grid (32 qtiles, 16 heads, 4 = b*2+chunk); 2 waves/block, 32 q-rows/wave,
// k-chunk = 1024 rows. p = exp(st - a*d) unnormalized (logits are O(5), fp32-safe);
// partials (bf16 o, fp32 l) merged by k_merge as (o0+o1)/(l0+l1).
__global__ __launch_bounds__(128) void k_attn(
    const ushort* __restrict__ Q, const ushort* __restrict__ K, const ushort* __restrict__ Vt,
    const ushort* __restrict__ AF, const ushort* __restrict__ BF,
    const float* __restrict__ dist_bias,
    ushort* __restrict__ op0, ushort* __restrict__ op1, float* __restrict__ lpart)
{
  const int tid = threadIdx.x, wave = tid>>6, lane = tid&63;
  const int qt = blockIdx.x, h = blockIdx.y, z = blockIdx.z;
  const int b = z>>1, c = z&1;
  const int lo5 = lane&31, hi = lane>>5;
  const float ah = fabsf(dist_bias[h]);
  const ushort* Qh  = Q  + ((size_t)(b*NHEADS+h))*NSEQ*DK;
  const ushort* Kh  = K  + ((size_t)(b*NHEADS+h))*NSEQ*DK;
  const ushort* Vth = Vt + ((size_t)(b*NHEADS+h))*DK*NSEQ;
  const ushort* AFb = AF + (size_t)b*NSEQ*16;
  const ushort* BFb = BF + (size_t)b*NSEQ*16;

  const int q0 = qt*64 + wave*32;

  short8 qf[4];
  #pragma unroll
  for (int s=0;s<4;s++)
    qf[s] = *(const short8*)&Qh[(size_t)(q0+lo5)*DK + s*16 + hi*8];
  const short8 bfq = *(const short8*)&BFb[(size_t)(q0+lo5)*16 + hi*8];

  f32x16 o0 = {}, o1 = {};
  float l_run = 0.f;
  const int j0 = c*1024;

  for (int jt=0; jt<32; ++jt){
    const int jb = j0 + jt*32;
    // ---- d^2 tile via MFMA ----
    const short8 afk = *(const short8*)&AFb[(size_t)(jb+lo5)*16 + hi*8];
    f32x16 zz = {};
    f32x16 d2 = __builtin_amdgcn_mfma_f32_32x32x16_bf16(afk, bfq, zz, 0,0,0);
    // ---- S^T = K Q^T (Q pre-scaled by 1/8) ----
    f32x16 st = {};
    #pragma unroll
    for (int s=0;s<4;s++){
      short8 kf = *(const short8*)&Kh[(size_t)(jb+lo5)*DK + s*16 + hi*8];
      st = __builtin_amdgcn_mfma_f32_32x32x16_bf16(kf, qf[s], st, 0,0,0);
    }
    // ---- V loads issued early (independent of softmax) ----
    const short8 v00 = *(const short8*)&Vth[(size_t)(lo5)*NSEQ      + jb      + hi*8];
    const short8 v01 = *(const short8*)&Vth[(size_t)(lo5)*NSEQ      + jb + 16 + hi*8];
    const short8 v10 = *(const short8*)&Vth[(size_t)(32+lo5)*NSEQ   + jb      + hi*8];
    const short8 v11 = *(const short8*)&Vth[(size_t)(32+lo5)*NSEQ   + jb + 16 + hi*8];
    // ---- p = exp(st - a*d), no max needed (logit range analysis) ----
    float p[16];
    #pragma unroll
    for (int r=0;r<16;r++){
      float d = __builtin_amdgcn_sqrtf(fmaxf(d2[r], 0.f));
      p[r] = __expf(fmaf(-ah, d, st[r]));
    }
    // row sum (tree) + cross-half
    float s01=p[0]+p[1], s23=p[2]+p[3], s45=p[4]+p[5], s67=p[6]+p[7];
    float s89=p[8]+p[9], sab=p[10]+p[11], scd=p[12]+p[13], sef=p[14]+p[15];
    float t0=s01+s23, t1=s45+s67, t2=s89+sab, t3=scd+sef;
    float rsum = (t0+t1)+(t2+t3);
    rsum += __shfl_xor(rsum, 32);
    l_run += rsum;
    // ---- P -> bf16 A-fragments (cvt_pk + permlane32_swap), PV ----
    #pragma unroll
    for (int s=0;s<2;s++){
      uint w0, w1, w2, w3;
      asm("v_cvt_pk_bf16_f32 %0, %1, %2" : "=v"(w0) : "v"(p[8*s+0]), "v"(p[8*s+1]));
      asm("v_cvt_pk_bf16_f32 %0, %1, %2" : "=v"(w2) : "v"(p[8*s+4]), "v"(p[8*s+5]));
      asm("v_cvt_pk_bf16_f32 %0, %1, %2" : "=v"(w1) : "v"(p[8*s+2]), "v"(p[8*s+3]));
      asm("v_cvt_pk_bf16_f32 %0, %1, %2" : "=v"(w3) : "v"(p[8*s+6]), "v"(p[8*s+7]));
      asm volatile("v_permlane32_swap_b32 %0, %1" : "+v"(w0), "+v"(w2));
      asm volatile("v_permlane32_swap_b32 %0, %1" : "+v"(w1), "+v"(w3));
      uint4 aw; aw.x = w0; aw.y = w1; aw.z = w2; aw.w = w3;
      const short8 pa = __builtin_bit_cast(short8, aw);
      if (s==0){
        o0 = __builtin_amdgcn_mfma_f32_32x32x16_bf16(pa, v00, o0, 0,0,0);
        o1 = __builtin_amdgcn_mfma_f32_32x32x16_bf16(pa, v10, o1, 0,0,0);
      } else {
        o0 = __builtin_amdgcn_mfma_f32_32x32x16_bf16(pa, v01, o0, 0,0,0);
        o1 = __builtin_amdgcn_mfma_f32_32x32x16_bf16(pa, v11, o1, 0,0,0);
      }
    }
  }
  // ---- store partials: o (bf16, [bh][q][64]) + l (fp32, [bh][q]) ----
  ushort* op = (c ? op1 : op0) + ((size_t)(b*NHEADS+h))*NSEQ*DK;
  #pragma unroll
  for (int r=0;r<16;r++){
    const int qr = q0 + (r&3) + 8*(r>>2) + 4*hi;
    op[(size_t)qr*DK + lo5]      = f2bf(o0[r]);
    op[(size_t)qr*DK + 32 + lo5] = f2bf(o1[r]);
  }
  if (hi==0)
    lpart[(size_t)c*(2*NHEADS*NSEQ) + (size_t)(b*NHEADS+h)*NSEQ + q0 + lo5] = l_run;
}

// ---------------- merge split-K partials -> O [b][q][h*64+d] bf16 ----------------
__global__ void k_merge(const ushort* __restrict__ op0, const ushort* __restrict__ op1,
                        const float* __restrict__ lpart, ushort* __restrict__ Ob){
  const int idx = blockIdx.x*blockDim.x + threadIdx.x;   // < 524288
  const int row = idx>>3, dg = idx&7;                    // row < 65536
  const int q = row & 2047, bh = row >> 11;
  const int b = bh >> 4, h = bh & 15;
  const size_t po = (size_t)row*64 + dg*8;
  const short8 a  = *(const short8*)&op0[po];
  const short8 b8 = *(const short8*)&op1[po];
  const float inv = 1.f/(lpart[row] + lpart[65536 + row]);
  ushort o[8];
  #pragma unroll
  for (int j=0;j<8;j++)
    o[j] = f2bf((bf2f((ushort)a[j]) + bf2f((ushort)b8[j]))*inv);
  *(short8*)&Ob[((size_t)b*NSEQ + q)*DMODEL + h*DK + dg*8] = *(short8*)&o[0];
}

extern "C" void kernel_launch(void* const* d_in, const int* in_sizes, int n_in,
                              void* d_out, int out_size, void* d_ws, size_t ws_size,
                              hipStream_t stream) {
  const float* x   = (const float*)d_in[0];
  const float* pos = (const float*)d_in[1];
  const float* Wq  = (const float*)d_in[2];
  const float* bq  = (const float*)d_in[3];
  const float* Wk  = (const float*)d_in[4];
  const float* bk  = (const float*)d_in[5];
  const float* Wv  = (const float*)d_in[6];
  const float* bv  = (const float*)d_in[7];
  const float* Wo  = (const float*)d_in[8];
  const float* bo  = (const float*)d_in[9];
  const float* db  = (const float*)d_in[10];
  float* out = (float*)d_out;

  // workspace layout (48 MB, regions reused across phases):
  // 0-8MB   : xb (x bf16)            -> opart chunk0 (after qkv gemm)
  // 8-10MB  : Wqb                    -> AF(128K) + BF(128K) + lpart(512K)
  // 10-12MB : Wkb   (dead after qkv gemm)
  // 12-14MB : Wvb   (dead after qkv gemm)
  // 14-16MB : Wob   (live until k_gemm_out)
  // 16-24MB : Qb                     -> merged O (after attn)
  // 24-32MB : Kb
  // 32-40MB : Vtb
  // 40-48MB : opart chunk1
  char* ws = (char*)d_ws;
  ushort* xb   = (ushort*)(ws);
  ushort* Wqb  = (ushort*)(ws + ((size_t)8<<20));
  ushort* Wkb  = (ushort*)(ws + ((size_t)10<<20));
  ushort* Wvb  = (ushort*)(ws + ((size_t)12<<20));
  ushort* Wob  = (ushort*)(ws + ((size_t)14<<20));
  ushort* Qb   = (ushort*)(ws + ((size_t)16<<20));
  ushort* Kb   = (ushort*)(ws + ((size_t)24<<20));
  ushort* Vtb  = (ushort*)(ws + ((size_t)32<<20));
  ushort* op1  = (ushort*)(ws + ((size_t)40<<20));
  ushort* op0  = xb;                                   // reuse after qkv gemm
  ushort* AFt  = Wqb;                                  // reuse after qkv gemm
  ushort* BFt  = (ushort*)(ws + ((size_t)8<<20) + (128<<10));
  float*  lpart= (float*) (ws + ((size_t)8<<20) + (256<<10));
  ushort* Omrg = Qb;                                   // reuse after attn

  k_cvt<<<4096, 256, 0, stream>>>((const float4*)x,  (ushort4*)xb,  1048576);
  k_cvt<<<1024, 256, 0, stream>>>((const float4*)Wq, (ushort4*)Wqb, 262144);
  k_cvt<<<1024, 256, 0, stream>>>((const float4*)Wk, (ushort4*)Wkb, 262144);
  k_cvt<<<1024, 256, 0, stream>>>((const float4*)Wv, (ushort4*)Wvb, 262144);
  k_cvt<<<1024, 256, 0, stream>>>((const float4*)Wo, (ushort4*)Wob, 262144);
  k_gemm_qkv<<<768, 256, 0, stream>>>(xb, Wqb, Wkb, Wvb, bq, bk, bv, Qb, Kb, Vtb);
  k_geo<<<16, 256, 0, stream>>>(pos, AFt, BFt, 2*NSEQ);
  k_attn<<<dim3(32,NHEADS,4), 128, 0, stream>>>(Qb, Kb, Vtb, AFt, BFt, db, op0, op1, lpart);
  k_merge<<<2048, 256, 0, stream>>>(op0, op1, lpart, Omrg);
  k_gemm_out<<<256, 256, 0, stream>>>(Omrg, Wob, bo, out);
}